// Round 1
// baseline (2530.684 us; speedup 1.0000x reference)
//
#include <hip/hip_runtime.h>

#define KCW 1024     // num codewords
#define DIM 64       // embedding dim
#define ROWS_BLK 256 // rows per block (2 stripes)
#define STRIPE 128   // rows per stripe
#define CWTILE 128   // codewords per LDS phase

typedef __attribute__((ext_vector_type(4))) float f32x4;

// ---------------------------------------------------------------------------
// Pre-kernel: cnorm[k] = sum_d codebook[k][d]^2   (1024 floats into d_ws)
// ---------------------------------------------------------------------------
__global__ void __launch_bounds__(256) vq_cnorm_kernel(const float* __restrict__ cb,
                                                       float* __restrict__ cnorm) {
    int k = blockIdx.x * blockDim.x + threadIdx.x;
    if (k < KCW) {
        const float4* c4 = (const float4*)(cb + (size_t)k * DIM);
        float s0 = 0.f, s1 = 0.f, s2 = 0.f, s3 = 0.f;
#pragma unroll
        for (int j = 0; j < DIM / 4; j += 4) {
            float4 a = c4[j + 0];
            float4 b = c4[j + 1];
            float4 c = c4[j + 2];
            float4 d = c4[j + 3];
            s0 += a.x * a.x + a.y * a.y + a.z * a.z + a.w * a.w;
            s1 += b.x * b.x + b.y * b.y + b.z * b.z + b.w * b.w;
            s2 += c.x * c.x + c.y * c.y + c.z * c.z + c.w * c.w;
            s3 += d.x * d.x + d.y * d.y + d.z * d.z + d.w * d.w;
        }
        cnorm[k] = (s0 + s1) + (s2 + s3);
    }
}

// sequential x,y,z,w chain — bit-identical association to prior rounds
#define DOT4ACC(acc, av, bv)                                               \
    acc = fmaf((av).w, (bv).w,                                             \
          fmaf((av).z, (bv).z,                                             \
          fmaf((av).y, (bv).y,                                             \
          fmaf((av).x, (bv).x, (acc)))));

// load a 4-col quad of B (cols m = 4h..4h+3) at k-slice k4v into buffer P
#define LOADQ(P, k4v, h)                                                   \
    {   const int kb_ = ((k4v) ^ tx2);                                     \
        P##0 = sC[bbase + kb_ + ((h) * 4 + 0) * 128];                      \
        P##1 = sC[bbase + kb_ + ((h) * 4 + 1) * 128];                      \
        P##2 = sC[bbase + kb_ + ((h) * 4 + 2) * 128];                      \
        P##3 = sC[bbase + kb_ + ((h) * 4 + 3) * 128]; }

// one micro-row n at k-slice k4v (A from registers) against quad buffer P
#define ROWQ(P, n, k4v)                                                    \
    DOT4ACC(q##n.x, areg[n][(k4v)], P##0)                                  \
    DOT4ACC(q##n.y, areg[n][(k4v)], P##1)                                  \
    DOT4ACC(q##n.z, areg[n][(k4v)], P##2)                                  \
    DOT4ACC(q##n.w, areg[n][(k4v)], P##3)

#define FMAQ(P, k4v) ROWQ(P, 0, (k4v)) ROWQ(P, 1, (k4v)) ROWQ(P, 2, (k4v)) \
                     ROWQ(P, 3, (k4v)) ROWQ(P, 4, (k4v)) ROWQ(P, 5, (k4v)) \
                     ROWQ(P, 6, (k4v)) ROWQ(P, 7, (k4v))

#define UPR(n, comp)                                                       \
    { float s_ = fmaf(-2.f, q##n.comp, cn_);                               \
      if (s_ < best##n) { best##n = s_; bidx##n = cwv_; } }

#define UPC(c, comp, h)                                                    \
    { const float cn_ = sCn[cnb + 8 * (4 * (h) + (c))];                    \
      const int cwv_ = cwbase + 8 * (4 * (h) + (c));                       \
      UPR(0, comp) UPR(1, comp) UPR(2, comp) UPR(3, comp)                  \
      UPR(4, comp) UPR(5, comp) UPR(6, comp) UPR(7, comp) }

#define UPQUAD(h) UPC(0, x, (h)) UPC(1, y, (h)) UPC(2, z, (h)) UPC(3, w, (h))

#define MERGEPUT(n)                                                        \
    { int rl = 64 * wr + ty + 8 * (n);                                     \
      sMs[rl * 16 + slot] = best##n; sMi[rl * 16 + slot] = bidx##n; }

// ---------------------------------------------------------------------------
// A-in-registers distance GEMM. Prior round: compiler allocated only 128
// VGPR and defeated the declared 32-f4 ping-pong -> load-wait-FMA serial
// (VALUBusy 56%, LDS pipe at parity with VALU, no overlap). Now each
// thread's 8 A-rows x 64 dims live in 128 VGPRs, loaded ONCE per stripe;
// the phase loop streams only B quads (4 ds_read_b128 per 128 FMAs) with
// an explicit 2-quad rotation. Per-phase split into two 4-col passes to
// keep acc at 32 VGPR: total ~230 VGPR under (256,2)'s 256 cap.
// FMA chain order (k4 ascending, dot4 x->y->z->w) and ascending-cw
// strict-< argmin are unchanged -> bit-exact vs prior passing kernel.
// LDS = 66,560 B (unchanged; 2 blocks/CU).
// ---------------------------------------------------------------------------
__global__ void __launch_bounds__(256, 2) vq_main_kernel(const float* __restrict__ x,
                                                         const float* __restrict__ cb,
                                                         const float* __restrict__ cnorm,
                                                         float* __restrict__ out_discrete,
                                                         float* __restrict__ out_quant) {
    __shared__ float4 sX[STRIPE * 16];   // 32768 B (merge arrays alias this)
    __shared__ float4 sC[CWTILE * 16];   // 32768 B
    __shared__ float sCn[CWTILE];        // 512 B
    __shared__ int sFinal[STRIPE];       // 512 B                 total 66560

    float* sMs = (float*)sX;                 // 128 rows x 16 slots scores
    int* sMi = ((int*)sX) + STRIPE * 16;     // 128 rows x 16 slots indices

    const int tid = threadIdx.x;
    const int wave = tid >> 6;
    const int lane = tid & 63;
    const int wr = wave >> 1;   // row-group 0..1  (64 rows each)
    const int wc = wave & 1;    // cw-group 0..1   (64 cws each)
    const int ty = lane >> 3;   // 0..7
    const int tx = lane & 7;    // 0..7

    const int row0 = blockIdx.x * ROWS_BLK;
    const float4* xg = (const float4*)x;
    const float4* cbg = (const float4*)cb;
    float4* od4 = (float4*)out_discrete;
    float4* oq4 = (float4*)out_quant;

    const int cnb = 64 * wc + tx;          // first cw of this thread in tile
    const int bbase = (64 * wc + tx) * 16; // f4 base of first micro-col
    const int ty2 = ty << 1;
    const int tx2 = tx << 1;
    const int slot = wc * 8 + tx;

    for (int s = 0; s < ROWS_BLK / STRIPE; ++s) {
        const int grow0 = row0 + s * STRIPE;

        __syncthreads();  // (A) prior stripe's sFinal/sMs readers done

        // ---- stage x-stripe: 128 rows x 16 f4, swizzled ----
#pragma unroll
        for (int i = 0; i < 8; ++i) {
            int e = i * 256 + tid;
            int r = e >> 4, ch = e & 15;
            sX[r * 16 + (ch ^ ((r & 7) << 1))] = xg[(size_t)(grow0 + r) * 16 + ch];
        }
        __syncthreads();  // (A2) sX staged

        // ---- hoist this thread's 8 A-rows (full 64 dims) into 128 VGPRs ----
        float4 areg[8][16];
#pragma unroll
        for (int n = 0; n < 8; ++n) {
            const int rb = (64 * wr + ty + 8 * n) * 16;
#pragma unroll
            for (int j = 0; j < 16; ++j)
                areg[n][j] = sX[rb + (j ^ ty2)];
        }

        float best0 = 3.4e38f, best1 = 3.4e38f, best2 = 3.4e38f, best3 = 3.4e38f;
        float best4 = 3.4e38f, best5 = 3.4e38f, best6 = 3.4e38f, best7 = 3.4e38f;
        int bidx0 = 0, bidx1 = 0, bidx2 = 0, bidx3 = 0;
        int bidx4 = 0, bidx5 = 0, bidx6 = 0, bidx7 = 0;

        for (int p = 0; p < KCW / CWTILE; ++p) {
            __syncthreads();  // (B) prior phase's sC/sCn readers done

            // ---- stage cw tile: 128 cw x 16 f4, swizzled ----
#pragma unroll
            for (int i = 0; i < 8; ++i) {
                int e = i * 256 + tid;
                int c = e >> 4, ch = e & 15;
                sC[c * 16 + (ch ^ ((c & 7) << 1))] =
                    cbg[(size_t)(p * CWTILE + c) * 16 + ch];
            }
            if (tid < CWTILE) sCn[tid] = cnorm[p * CWTILE + tid];
            __syncthreads();  // (C) tile staged

            const int cwbase = p * CWTILE + 64 * wc + tx;

            // ---- two 4-col passes; A is register-resident, only B streams ----
#pragma unroll
            for (int h = 0; h < 2; ++h) {
                float4 q0 = {0.f, 0.f, 0.f, 0.f}, q1 = {0.f, 0.f, 0.f, 0.f};
                float4 q2 = {0.f, 0.f, 0.f, 0.f}, q3 = {0.f, 0.f, 0.f, 0.f};
                float4 q4 = {0.f, 0.f, 0.f, 0.f}, q5 = {0.f, 0.f, 0.f, 0.f};
                float4 q6 = {0.f, 0.f, 0.f, 0.f}, q7 = {0.f, 0.f, 0.f, 0.f};

                float4 u0, u1, u2, u3;   // quad ping
                float4 v0, v1, v2, v3;   // quad pong

                LOADQ(u, 0, h)
#pragma unroll
                for (int k4 = 0; k4 < 16; k4 += 2) {
                    LOADQ(v, k4 + 1, h)     // issue k4+1 while k4 computes
                    FMAQ(u, k4)             // 128 FMAs cover the v loads
                    if (k4 + 2 < 16) LOADQ(u, k4 + 2, h)
                    FMAQ(v, k4 + 1)         // 128 FMAs cover the u loads
                }

                // scores + running argmin (cw ascending -> strict < keeps
                // earliest index, matching np.argmin)
                UPQUAD(h)
            }
        }

        __syncthreads();  // (D) compute done -> safe to alias sX with merge

        MERGEPUT(0) MERGEPUT(1) MERGEPUT(2) MERGEPUT(3)
        MERGEPUT(4) MERGEPUT(5) MERGEPUT(6) MERGEPUT(7)
        __syncthreads();  // (E)

        if (tid < STRIPE) {
            float bs = sMs[tid * 16];
            int bi = sMi[tid * 16];
#pragma unroll
            for (int j = 1; j < 16; ++j) {
                float sj = sMs[tid * 16 + j];
                int ij = sMi[tid * 16 + j];
                if (sj < bs || (sj == bs && ij < bi)) { bs = sj; bi = ij; }
            }
            sFinal[tid] = bi;
        }
        __syncthreads();  // (F)

        // ---- epilogue: nontemporal streaming stores (outputs never re-read;
        //      keep the 600 MB write stream out of L2) ----
        {
            size_t obase = (size_t)grow0 * (KCW / 4);
            const int col = tid * 4;
            for (int it = 0; it < STRIPE; ++it) {
                int idx = sFinal[it];  // block-uniform per iteration
                f32x4 v;
                v.x = (col + 0 == idx) ? 1.f : 0.f;
                v.y = (col + 1 == idx) ? 1.f : 0.f;
                v.z = (col + 2 == idx) ? 1.f : 0.f;
                v.w = (col + 3 == idx) ? 1.f : 0.f;
                __builtin_nontemporal_store(v, (f32x4*)&od4[obase + (size_t)it * 256 + tid]);
            }
            size_t qbase = (size_t)grow0 * 16;
#pragma unroll
            for (int it = 0; it < 8; ++it) {
                int cnk = it * 256 + tid;
                int r = cnk >> 4;
                int ch = cnk & 15;
                float4 qv = cbg[(size_t)sFinal[r] * 16 + ch];
                __builtin_nontemporal_store(*(f32x4*)&qv, (f32x4*)&oq4[qbase + cnk]);
            }
        }
    }
}

// ---------------------------------------------------------------------------
extern "C" void kernel_launch(void* const* d_in, const int* in_sizes, int n_in,
                              void* d_out, int out_size, void* d_ws, size_t ws_size,
                              hipStream_t stream) {
    const float* x = (const float*)d_in[0];
    const float* cb = (const float*)d_in[1];
    float* cnorm = (float*)d_ws;  // 1024 floats of scratch

    const int n = in_sizes[0];    // 8388608
    const int rows = n / DIM;     // 131072

    float* out_discrete = (float*)d_out;
    float* out_quant = (float*)d_out + (size_t)rows * KCW;

    vq_cnorm_kernel<<<(KCW + 255) / 256, 256, 0, stream>>>(cb, cnorm);
    vq_main_kernel<<<rows / ROWS_BLK, 256, 0, stream>>>(x, cb, cnorm, out_discrete, out_quant);
}

// Round 2
// 815.368 us; speedup vs baseline: 3.1037x; 3.1037x over previous
//
#include <hip/hip_runtime.h>

#define KCW 1024     // num codewords
#define DIM 64       // embedding dim
#define ROWS_BLK 256 // rows per block (2 stripes)
#define STRIPE 128   // rows per stripe
#define CWTILE 128   // codewords per LDS phase

typedef __attribute__((ext_vector_type(4))) float f32x4;

// ---------------------------------------------------------------------------
// Pre-kernel: cnorm[k] = sum_d codebook[k][d]^2   (1024 floats into d_ws)
// ---------------------------------------------------------------------------
__global__ void __launch_bounds__(256) vq_cnorm_kernel(const float* __restrict__ cb,
                                                       float* __restrict__ cnorm) {
    int k = blockIdx.x * blockDim.x + threadIdx.x;
    if (k < KCW) {
        const float4* c4 = (const float4*)(cb + (size_t)k * DIM);
        float s0 = 0.f, s1 = 0.f, s2 = 0.f, s3 = 0.f;
#pragma unroll
        for (int j = 0; j < DIM / 4; j += 4) {
            float4 a = c4[j + 0];
            float4 b = c4[j + 1];
            float4 c = c4[j + 2];
            float4 d = c4[j + 3];
            s0 += a.x * a.x + a.y * a.y + a.z * a.z + a.w * a.w;
            s1 += b.x * b.x + b.y * b.y + b.z * b.z + b.w * b.w;
            s2 += c.x * c.x + c.y * c.y + c.z * c.z + c.w * c.w;
            s3 += d.x * d.x + d.y * d.y + d.z * d.z + d.w * d.w;
        }
        cnorm[k] = (s0 + s1) + (s2 + s3);
    }
}

// sequential x,y,z,w chain — bit-identical association to prior passing rounds
#define DOT4ACC(acc, av, bv)                                               \
    acc = fmaf((av).w, (bv).w,                                             \
          fmaf((av).z, (bv).z,                                             \
          fmaf((av).y, (bv).y,                                             \
          fmaf((av).x, (bv).x, (acc)))));

// one micro-row n against all 8 col fragments of buffer P
#define ROWF(P, n)                                                         \
    DOT4ACC(q##n##a.x, r##P##n, c##P##0) DOT4ACC(q##n##a.y, r##P##n, c##P##1) \
    DOT4ACC(q##n##a.z, r##P##n, c##P##2) DOT4ACC(q##n##a.w, r##P##n, c##P##3) \
    DOT4ACC(q##n##b.x, r##P##n, c##P##4) DOT4ACC(q##n##b.y, r##P##n, c##P##5) \
    DOT4ACC(q##n##b.z, r##P##n, c##P##6) DOT4ACC(q##n##b.w, r##P##n, c##P##7)

#define FMAB(P) ROWF(P, 0) ROWF(P, 1) ROWF(P, 2) ROWF(P, 3)                \
                ROWF(P, 4) ROWF(P, 5) ROWF(P, 6) ROWF(P, 7)

// load one k4-slice of operands (8 A-rows + 8 B-cols) into buffer P's regs
#define LOADOPS(P, k4v)                                                    \
    {   const int ka_ = (k4v) ^ ty2;                                       \
        const int kb_ = (k4v) ^ tx2;                                       \
        r##P##0 = sX[abase + ka_ + 0 * 128];                               \
        r##P##1 = sX[abase + ka_ + 1 * 128];                               \
        r##P##2 = sX[abase + ka_ + 2 * 128];                               \
        r##P##3 = sX[abase + ka_ + 3 * 128];                               \
        r##P##4 = sX[abase + ka_ + 4 * 128];                               \
        r##P##5 = sX[abase + ka_ + 5 * 128];                               \
        r##P##6 = sX[abase + ka_ + 6 * 128];                               \
        r##P##7 = sX[abase + ka_ + 7 * 128];                               \
        c##P##0 = sC[bbase + kb_ + 0 * 128];                               \
        c##P##1 = sC[bbase + kb_ + 1 * 128];                               \
        c##P##2 = sC[bbase + kb_ + 2 * 128];                               \
        c##P##3 = sC[bbase + kb_ + 3 * 128];                               \
        c##P##4 = sC[bbase + kb_ + 4 * 128];                               \
        c##P##5 = sC[bbase + kb_ + 5 * 128];                               \
        c##P##6 = sC[bbase + kb_ + 6 * 128];                               \
        c##P##7 = sC[bbase + kb_ + 7 * 128]; }

#define UPROW(n, X)                                                        \
    { float s_ = fmaf(-2.f, q##n##X, cn);                                  \
      if (s_ < best##n) { best##n = s_; bidx##n = cwv; } }

#define UPCOL(c, X)                                                        \
    { const float cn = sCn[cnb + 8 * (c)];                                 \
      const int cwv = cwbase + 8 * (c);                                    \
      UPROW(0, X) UPROW(1, X) UPROW(2, X) UPROW(3, X)                      \
      UPROW(4, X) UPROW(5, X) UPROW(6, X) UPROW(7, X) }

#define MERGEPUT(n)                                                        \
    { int rl = 64 * wr + ty + 8 * (n);                                     \
      sMs[rl * 16 + slot] = best##n; sMi[rl * 16 + slot] = bidx##n; }

// ---------------------------------------------------------------------------
// Register-tiled distance GEMM, streaming argmin, explicit k4 ping-pong.
// R0 post-mortem: allocator pinned 128 VGPR (its 4-wave/SIMD comfort point)
// and rematerialized the ping-pong loads next to their uses -> load-wait-FMA
// serial, VALUBusy 56%. R1 post-mortem: float4 areg[8][16] (2KB/thread)
// blew the SROA threshold -> scratch -> 4 GB FETCH, 5.4x regression.
// This round: occupancy is LDS-capped at 2 blocks/CU (66560 B) anyway, so
// amdgpu_waves_per_eu(2,2) tells the allocator regs 129..256 are free.
// Named-scalar ping-pong (32 f4 operands + 16 f4 acc ~ 224 VGPR) should now
// stay live: k4's 512 FMA cycles hide k4+1's 16 ds_read_b128.
// Floors: LDS pipe ~164 us, VALU ~109 us, HBM ~119 us (writes overlap).
// ---------------------------------------------------------------------------
__global__ void __launch_bounds__(256)
__attribute__((amdgpu_waves_per_eu(2, 2)))
vq_main_kernel(const float* __restrict__ x,
               const float* __restrict__ cb,
               const float* __restrict__ cnorm,
               float* __restrict__ out_discrete,
               float* __restrict__ out_quant) {
    __shared__ float4 sX[STRIPE * 16];   // 32768 B (merge arrays alias this)
    __shared__ float4 sC[CWTILE * 16];   // 32768 B
    __shared__ float sCn[CWTILE];        // 512 B
    __shared__ int sFinal[STRIPE];       // 512 B                 total 66560

    float* sMs = (float*)sX;                 // 128 rows x 16 slots scores
    int* sMi = ((int*)sX) + STRIPE * 16;     // 128 rows x 16 slots indices

    const int tid = threadIdx.x;
    const int wave = tid >> 6;
    const int lane = tid & 63;
    const int wr = wave >> 1;   // row-group 0..1  (64 rows each)
    const int wc = wave & 1;    // cw-group 0..1   (64 cws each)
    const int ty = lane >> 3;   // 0..7
    const int tx = lane & 7;    // 0..7

    const int row0 = blockIdx.x * ROWS_BLK;
    const float4* xg = (const float4*)x;
    const float4* cbg = (const float4*)cb;
    float4* od4 = (float4*)out_discrete;
    float4* oq4 = (float4*)out_quant;

    const int cnb = 64 * wc + tx;          // first cw of this thread in tile
    const int abase = (64 * wr + ty) * 16; // f4 base of first micro-row
    const int bbase = (64 * wc + tx) * 16; // f4 base of first micro-col
    const int ty2 = ty << 1;
    const int tx2 = tx << 1;
    const int slot = wc * 8 + tx;

    for (int s = 0; s < ROWS_BLK / STRIPE; ++s) {
        const int grow0 = row0 + s * STRIPE;

        __syncthreads();  // (A) prior stripe's sFinal/sMs readers done

        // ---- stage x-stripe: 128 rows x 16 f4, swizzled ----
#pragma unroll
        for (int i = 0; i < 8; ++i) {
            int e = i * 256 + tid;
            int r = e >> 4, ch = e & 15;
            sX[r * 16 + (ch ^ ((r & 7) << 1))] = xg[(size_t)(grow0 + r) * 16 + ch];
        }

        float best0 = 3.4e38f, best1 = 3.4e38f, best2 = 3.4e38f, best3 = 3.4e38f;
        float best4 = 3.4e38f, best5 = 3.4e38f, best6 = 3.4e38f, best7 = 3.4e38f;
        int bidx0 = 0, bidx1 = 0, bidx2 = 0, bidx3 = 0;
        int bidx4 = 0, bidx5 = 0, bidx6 = 0, bidx7 = 0;

        for (int p = 0; p < KCW / CWTILE; ++p) {
            __syncthreads();  // (B) prior phase's sC/sCn readers done

            // ---- stage cw tile: 128 cw x 16 f4, swizzled ----
#pragma unroll
            for (int i = 0; i < 8; ++i) {
                int e = i * 256 + tid;
                int c = e >> 4, ch = e & 15;
                sC[c * 16 + (ch ^ ((c & 7) << 1))] =
                    cbg[(size_t)(p * CWTILE + c) * 16 + ch];
            }
            if (tid < CWTILE) sCn[tid] = cnorm[p * CWTILE + tid];
            __syncthreads();  // (C) tile staged (covers sX for p==0 too)

            float4 q0a = {0.f, 0.f, 0.f, 0.f}, q0b = {0.f, 0.f, 0.f, 0.f};
            float4 q1a = {0.f, 0.f, 0.f, 0.f}, q1b = {0.f, 0.f, 0.f, 0.f};
            float4 q2a = {0.f, 0.f, 0.f, 0.f}, q2b = {0.f, 0.f, 0.f, 0.f};
            float4 q3a = {0.f, 0.f, 0.f, 0.f}, q3b = {0.f, 0.f, 0.f, 0.f};
            float4 q4a = {0.f, 0.f, 0.f, 0.f}, q4b = {0.f, 0.f, 0.f, 0.f};
            float4 q5a = {0.f, 0.f, 0.f, 0.f}, q5b = {0.f, 0.f, 0.f, 0.f};
            float4 q6a = {0.f, 0.f, 0.f, 0.f}, q6b = {0.f, 0.f, 0.f, 0.f};
            float4 q7a = {0.f, 0.f, 0.f, 0.f}, q7b = {0.f, 0.f, 0.f, 0.f};

            // ping-pong operand buffers A/B (32 float4 = 128 VGPRs)
            float4 rA0, rA1, rA2, rA3, rA4, rA5, rA6, rA7;
            float4 cA0, cA1, cA2, cA3, cA4, cA5, cA6, cA7;
            float4 rB0, rB1, rB2, rB3, rB4, rB5, rB6, rB7;
            float4 cB0, cB1, cB2, cB3, cB4, cB5, cB6, cB7;

            LOADOPS(A, 0)
#pragma unroll
            for (int k4 = 0; k4 < 16; k4 += 2) {
                LOADOPS(B, k4 + 1)   // issue k4+1 loads before k4's FMAs
                FMAB(A)
                if (k4 + 2 < 16) LOADOPS(A, k4 + 2)
                FMAB(B)
            }

            // ---- scores + running argmin (cw ascending -> strict < keeps
            //      earliest index, matching np.argmin) ----
            const int cwbase = p * CWTILE + 64 * wc + tx;
            UPCOL(0, a.x) UPCOL(1, a.y) UPCOL(2, a.z) UPCOL(3, a.w)
            UPCOL(4, b.x) UPCOL(5, b.y) UPCOL(6, b.z) UPCOL(7, b.w)
        }

        __syncthreads();  // (D) compute done -> safe to alias sX with merge

        MERGEPUT(0) MERGEPUT(1) MERGEPUT(2) MERGEPUT(3)
        MERGEPUT(4) MERGEPUT(5) MERGEPUT(6) MERGEPUT(7)
        __syncthreads();  // (E)

        if (tid < STRIPE) {
            float bs = sMs[tid * 16];
            int bi = sMi[tid * 16];
#pragma unroll
            for (int j = 1; j < 16; ++j) {
                float sj = sMs[tid * 16 + j];
                int ij = sMi[tid * 16 + j];
                if (sj < bs || (sj == bs && ij < bi)) { bs = sj; bi = ij; }
            }
            sFinal[tid] = bi;
        }
        __syncthreads();  // (F)

        // ---- epilogue: nontemporal streaming stores (outputs never re-read;
        //      keep the 600 MB write stream out of L2) ----
        {
            size_t obase = (size_t)grow0 * (KCW / 4);
            const int col = tid * 4;
            for (int it = 0; it < STRIPE; ++it) {
                int idx = sFinal[it];  // block-uniform per iteration
                f32x4 v;
                v.x = (col + 0 == idx) ? 1.f : 0.f;
                v.y = (col + 1 == idx) ? 1.f : 0.f;
                v.z = (col + 2 == idx) ? 1.f : 0.f;
                v.w = (col + 3 == idx) ? 1.f : 0.f;
                __builtin_nontemporal_store(v, (f32x4*)&od4[obase + (size_t)it * 256 + tid]);
            }
            size_t qbase = (size_t)grow0 * 16;
#pragma unroll
            for (int it = 0; it < 8; ++it) {
                int cnk = it * 256 + tid;
                int r = cnk >> 4;
                int ch = cnk & 15;
                float4 qv = cbg[(size_t)sFinal[r] * 16 + ch];
                __builtin_nontemporal_store(*(f32x4*)&qv, (f32x4*)&oq4[qbase + cnk]);
            }
        }
    }
}

// ---------------------------------------------------------------------------
extern "C" void kernel_launch(void* const* d_in, const int* in_sizes, int n_in,
                              void* d_out, int out_size, void* d_ws, size_t ws_size,
                              hipStream_t stream) {
    const float* x = (const float*)d_in[0];
    const float* cb = (const float*)d_in[1];
    float* cnorm = (float*)d_ws;  // 1024 floats of scratch

    const int n = in_sizes[0];    // 8388608
    const int rows = n / DIM;     // 131072

    float* out_discrete = (float*)d_out;
    float* out_quant = (float*)d_out + (size_t)rows * KCW;

    vq_cnorm_kernel<<<(KCW + 255) / 256, 256, 0, stream>>>(cb, cnorm);
    vq_main_kernel<<<rows / ROWS_BLK, 256, 0, stream>>>(x, cb, cnorm, out_discrete, out_quant);
}